// Round 5
// baseline (981.892 us; speedup 1.0000x reference)
//
#include <hip/hip_runtime.h>
#include <cstdint>

typedef unsigned int u32;
typedef unsigned short u16;
typedef __bf16 bf16x8 __attribute__((ext_vector_type(8)));
typedef float f32x4 __attribute__((ext_vector_type(4)));

#define NTOK 4096
#define HDIM 2048
#define FMOE 1024
#define FSH  2048
#define NEXP 16

__device__ __forceinline__ u16 f2bf(float f) {
  u32 u = __float_as_uint(f);
  u32 r = (u + 0x7fffu + ((u >> 16) & 1u)) >> 16;
  return (u16)r;
}
__device__ __forceinline__ float bf2f(u16 h) {
  return __uint_as_float(((u32)h) << 16);
}

__device__ __forceinline__ void gld_lds16(const void* g, void* l) {
  __builtin_amdgcn_global_load_lds(
      (const __attribute__((address_space(1))) u32*)g,
      (__attribute__((address_space(3))) u32*)l, 16, 0, 0);
}

// ---------------- fp32 -> bf16 conversion (vectorized x4) ----------------
__global__ void cvt_bf16(const float* __restrict__ in, u16* __restrict__ out, long n4) {
  long i = (long)blockIdx.x * blockDim.x + threadIdx.x;
  if (i < n4) {
    float4 v = ((const float4*)in)[i];
    ushort4 o;
    o.x = f2bf(v.x); o.y = f2bf(v.y); o.z = f2bf(v.z); o.w = f2bf(v.w);
    ((ushort4*)out)[i] = o;
  }
}

// ---------------- gate+up -> INTERLEAVED layout ----------------
// dst rows per 256-chunk c: [256c,256c+128) = gate f in [128c,128c+128);
//                           [256c+128,256c+256) = up, same f range.
// This makes every 256-col N-tile of the GU GEMM self-contained for silu fusion.
template <int F>
__global__ void cvt_pair(const float* __restrict__ g, const float* __restrict__ u,
                         u16* __restrict__ dst) {
  int e = blockIdx.z;
  const long n4 = (long)F * HDIM / 4;
  long i = (long)blockIdx.x * blockDim.x + threadIdx.x;
  if (i >= n4) return;
  int f = (int)(i >> 9);           // HDIM/4 = 512
  int c = (int)(i & 511);
  const float4* gs = (const float4*)(g + (long)e * F * HDIM);
  const float4* us = (const float4*)(u + (long)e * F * HDIM);
  ushort4* d = (ushort4*)(dst + (long)e * 2 * F * HDIM);
  long rg = (long)(256 * (f >> 7) + (f & 127)) * 512 + c;
  long ru = rg + 128 * 512;
  float4 v = gs[i];
  ushort4 o;
  o.x = f2bf(v.x); o.y = f2bf(v.y); o.z = f2bf(v.z); o.w = f2bf(v.w);
  d[rg] = o;
  v = us[i];
  o.x = f2bf(v.x); o.y = f2bf(v.y); o.z = f2bf(v.z); o.w = f2bf(v.w);
  d[ru] = o;
}

// ---------------- routing v4: one wave per token, NO LDS, NO barriers ----------------
// gw is 128 KB -> L2-hot; each wave streams it directly. Removes the 128KB-LDS-per-4-tokens
// staging + 4 syncthreads of v3 (suspected large hidden cost below top-5 cut).
__global__ __launch_bounds__(256) void routing_kernel(
    const float* __restrict__ hidden, const float* __restrict__ gw,
    const float* __restrict__ bias, int* __restrict__ topk_idx,
    float* __restrict__ topk_w) {
  int tid = threadIdx.x, lane = tid & 63, wv = tid >> 6;
  int t = blockIdx.x * 4 + wv;
  const float4* h4 = (const float4*)(hidden + (long)t * HDIM);
  const float4* g4 = (const float4*)gw;
  float4 hv[8];
#pragma unroll
  for (int j = 0; j < 8; ++j) hv[j] = h4[lane + 64 * j];
  float acc[NEXP];
#pragma unroll
  for (int e = 0; e < NEXP; ++e) {
    float a = 0.f;
#pragma unroll
    for (int j = 0; j < 8; ++j) {
      float4 g = g4[e * 512 + lane + 64 * j];
      a += hv[j].x * g.x + hv[j].y * g.y + hv[j].z * g.z + hv[j].w * g.w;
    }
    acc[e] = a;
  }
#pragma unroll
  for (int n = 0; n < NEXP; ++n) {
    float v = acc[n];
    for (int m = 32; m; m >>= 1) v += __shfl_xor(v, m);
    acc[n] = v;
  }
  if (lane == 0) {
    float sc[NEXP], scb[NEXP];
#pragma unroll
    for (int n = 0; n < NEXP; ++n) {
      sc[n] = 1.f / (1.f + expf(-acc[n]));
      scb[n] = sc[n] + bias[n];
    }
    float gs[4];
#pragma unroll
    for (int g = 0; g < 4; ++g) {
      float m1 = -1e30f, m2 = -1e30f;
#pragma unroll
      for (int j = 0; j < 4; ++j) {
        float v = scb[4 * g + j];
        if (v > m1) { m2 = m1; m1 = v; } else if (v > m2) { m2 = v; }
      }
      gs[g] = m1 + m2;
    }
    int g1 = -1, g2 = -1;
    { float b = -1e30f; for (int g = 0; g < 4; ++g) if (gs[g] > b) { b = gs[g]; g1 = g; } }
    { float b = -1e30f; for (int g = 0; g < 4; ++g) if (g != g1 && gs[g] > b) { b = gs[g]; g2 = g; } }
    bool used[NEXP];
#pragma unroll
    for (int n = 0; n < NEXP; ++n) used[n] = false;
    int sel[4]; float wts[4]; float s = 0.f;
    for (int k = 0; k < 4; ++k) {
      float b = -1e30f; int bi = 0;
      for (int n = 0; n < NEXP; ++n) {
        int g = n >> 2;
        if ((g == g1 || g == g2) && !used[n] && scb[n] > b) { b = scb[n]; bi = n; }
      }
      used[bi] = true; sel[k] = bi; wts[k] = sc[bi]; s += sc[bi];
    }
    float inv = 2.5f / (s + 1e-20f);
    for (int k = 0; k < 4; ++k) {
      topk_idx[t * 4 + k] = sel[k];
      topk_w[t * 4 + k] = wts[k] * inv;
    }
  }
}

// ---------------- histogram + prefix in one small kernel (no atomics) ----------------
__global__ __launch_bounds__(256) void count_prefix(const int* __restrict__ topki,
                                                    int* __restrict__ offs) {
  __shared__ int wsum[4][NEXP];
  int tid = threadIdx.x, lane = tid & 63, wv = tid >> 6;
  int c[NEXP];
#pragma unroll
  for (int e = 0; e < NEXP; ++e) c[e] = 0;
  for (int i0 = wv * 64; i0 < NTOK * 4; i0 += 256) {
    int v = topki[i0 + lane];
#pragma unroll
    for (int e = 0; e < NEXP; ++e) {
      unsigned long long b = __ballot(v == e);
      if (lane == 0) c[e] += __popcll(b);
    }
  }
  if (lane == 0) {
#pragma unroll
    for (int e = 0; e < NEXP; ++e) wsum[wv][e] = c[e];
  }
  __syncthreads();
  if (tid == 0) {
    int s = 0;
    for (int e = 0; e < NEXP; ++e) {
      int t = wsum[0][e] + wsum[1][e] + wsum[2][e] + wsum[3][e];
      offs[e] = s;
      s += t;
    }
    offs[NEXP] = s;
  }
}

// ---------------- deterministic ordered compaction + slot map ----------------
__global__ void fill_lists(const int* __restrict__ topk_idx,
                           const int* __restrict__ offs, int* __restrict__ ltok,
                           int* __restrict__ slotmap) {
  int e = blockIdx.x;
  int tid = threadIdx.x, lane = tid & 63, wv = tid >> 6;
  __shared__ int cursor;
  __shared__ int wcnt[4];
  if (tid == 0) cursor = offs[e];
  __syncthreads();
  for (int base = 0; base < NTOK; base += 256) {
    int t = base + tid;
    int flag = 0, kk = 0;
#pragma unroll
    for (int k = 0; k < 4; ++k) {
      if (topk_idx[t * 4 + k] == e) { flag = 1; kk = k; }
    }
    unsigned long long b = __ballot(flag);
    if (lane == 0) wcnt[wv] = __popcll(b);
    __syncthreads();
    int pre = 0;
    for (int i = 0; i < wv; ++i) pre += wcnt[i];
    int pos = cursor + pre + __popcll(b & ((1ull << lane) - 1ull));
    if (flag) { ltok[pos] = t; slotmap[t * 4 + kk] = pos; }
    __syncthreads();
    if (tid == 0) cursor += wcnt[0] + wcnt[1] + wcnt[2] + wcnt[3];
    __syncthreads();
  }
}

// ---------------- final reduce ----------------
__global__ void reduce_out(const u16* __restrict__ SY, const u16* __restrict__ Y,
                           const int* __restrict__ slotmap, const float* __restrict__ tkw,
                           float* __restrict__ out) {
  long i = (long)blockIdx.x * blockDim.x + threadIdx.x;  // over NTOK*HDIM/4
  int t = (int)(i >> 9);       // HDIM/4 = 512
  int c4 = (int)(i & 511);
  ushort4 s = ((const ushort4*)SY)[i];
  float4 o;
  o.x = bf2f(s.x); o.y = bf2f(s.y); o.z = bf2f(s.z); o.w = bf2f(s.w);
#pragma unroll
  for (int k = 0; k < 4; ++k) {
    int sl = slotmap[t * 4 + k];
    float w = tkw[t * 4 + k];
    ushort4 y = ((const ushort4*)Y)[(long)sl * 512 + c4];
    o.x += w * bf2f(y.x);
    o.y += w * bf2f(y.y);
    o.z += w * bf2f(y.z);
    o.w += w * bf2f(y.w);
  }
  ((float4*)out)[i] = o;
}

// ================= 256x256 bf16 GEMM-BT, 8-phase counted-vmcnt schedule (v3) =================
// K-loop identical to round-4 verified version. New: fuse flag -- when 1, B is the
// interleaved gate|up layout and the epilogue computes silu(g)*u via LDS exchange:
// up-waves (wn>=2) park u as bf16 in LDS (even buffer, free after final iteration),
// gate-waves (wn<2) read it and store compact bf16 activations (ldc = N/2).
#define LGKM0 asm volatile("s_waitcnt lgkmcnt(0)" ::: "memory")
#define VMC4  asm volatile("s_waitcnt vmcnt(4)" ::: "memory")
#define VMC0  asm volatile("s_waitcnt vmcnt(0)" ::: "memory")
__device__ __forceinline__ void bar() {
  asm volatile("" ::: "memory");
  __builtin_amdgcn_s_barrier();
  asm volatile("" ::: "memory");
}

__global__ __launch_bounds__(512, 2) void gemm256(
    const u16* __restrict__ A, const u16* __restrict__ B, u16* __restrict__ C,
    const int* __restrict__ gather, const int* __restrict__ offs,
    int Mstatic, int N, int K, int lda, long Bstride, int fuse) {
  int e = blockIdx.z;
  int seg0 = 0, segM = Mstatic;
  if (offs) { seg0 = offs[e]; segM = offs[e + 1] - seg0; }
  int mt = blockIdx.y, nt = blockIdx.x;
  if (mt * 256 >= segM) return;
  const u16* Be = B + (long)e * Bstride;

  __shared__ __align__(16) u16 sm[65536];  // 128 KiB -> 1 block/CU

  int tid = threadIdx.x;
  int lane = tid & 63;
  int wv = tid >> 6, wm = wv >> 2, wn = wv & 3;
  int c4 = lane & 15, r4 = lane >> 4;

  // ---- staging addressing: thread covers (row = j*64 + tid>>3, chunk = tid&7) of a half-tile
  int srow = tid >> 3, schunk = tid & 7;
  int sswz8 = (schunk ^ (srow & 7)) * 8;   // pre-swizzled source col chunk
  int sOff = srow * 64 + schunk * 8;       // linear LDS dest

  u32 aoff[2][2], boff[2][2];              // element offsets, (h, j)
#pragma unroll
  for (int h = 0; h < 2; ++h)
#pragma unroll
    for (int j = 0; j < 2; ++j) {
      int rit = h * 128 + j * 64 + srow;
      int rl = mt * 256 + rit;
      if (rl >= segM) rl = mt * 256;       // clamp (masked at store)
      int ridx = seg0 + rl;
      u32 arow = gather ? (u32)gather[ridx] : (u32)ridx;
      aoff[h][j] = arow * (u32)lda + (u32)sswz8;
      boff[h][j] = (u32)(nt * 256 + rit) * (u32)K + (u32)sswz8;
    }

  // ---- ds_read lane addressing (row&7 == lane&7 for all frags)
  int swzv = (lane & 7) * 8;
  int aRL0 = c4 * 64 + ((r4 * 8) ^ swzv);  // kk=0
  int aRL1 = aRL0 ^ 32;                    // kk=1
  int aB0 = wm * 8192, aB1 = 32768 + aB0;
  int bB0 = 16384 + wn * 4096, bB1 = 32768 + bB0;

  f32x4 acc[8][4];
  bf16x8 af[4][2], bLo[2][2], bHi[2][2];
#pragma unroll
  for (int i = 0; i < 8; ++i)
#pragma unroll
    for (int j = 0; j < 4; ++j) acc[i][j] = f32x4{0.f, 0.f, 0.f, 0.f};

#define READ_A8(BASE) do { _Pragma("unroll") \
  for (int mi = 0; mi < 4; ++mi) { \
    af[mi][0] = *(const bf16x8*)&sm[(BASE) + mi * 1024 + aRL0]; \
    af[mi][1] = *(const bf16x8*)&sm[(BASE) + mi * 1024 + aRL1]; \
  } } while (0)
#define READ_B4(BASE, BARR) do { _Pragma("unroll") \
  for (int ni = 0; ni < 2; ++ni) { \
    BARR[ni][0] = *(const bf16x8*)&sm[(BASE) + ni * 1024 + aRL0]; \
    BARR[ni][1] = *(const bf16x8*)&sm[(BASE) + ni * 1024 + aRL1]; \
  } } while (0)
#define MFMAQ(MI0, NI0, BARR) do { __builtin_amdgcn_s_setprio(1); \
  _Pragma("unroll") for (int mi = 0; mi < 4; ++mi) \
  _Pragma("unroll") for (int ni = 0; ni < 2; ++ni) \
  _Pragma("unroll") for (int kk = 0; kk < 2; ++kk) \
    acc[(MI0) + mi][(NI0) + ni] = __builtin_amdgcn_mfma_f32_16x16x32_bf16( \
        af[mi][kk], BARR[ni][kk], acc[(MI0) + mi][(NI0) + ni], 0, 0, 0); \
  __builtin_amdgcn_s_setprio(0); } while (0)
#define STAGE_A(PO, H, T) do { \
  gld_lds16(A + aoff[H][0] + (u32)((T) * 64), &sm[(PO) + (H) * 8192 + sOff]); \
  gld_lds16(A + aoff[H][1] + (u32)((T) * 64), &sm[(PO) + (H) * 8192 + 4096 + sOff]); \
} while (0)
#define STAGE_B(PO, H, T) do { \
  gld_lds16(Be + boff[H][0] + (u32)((T) * 64), &sm[(PO) + 16384 + (H) * 8192 + sOff]); \
  gld_lds16(Be + boff[H][1] + (u32)((T) * 64), &sm[(PO) + 16384 + (H) * 8192 + 4096 + sOff]); \
} while (0)

  // ---- prologue: tile0 (4 halves) + B of tile1 (2 halves); A of tile1 staged at ph1/ph2
  STAGE_A(0, 0, 0); STAGE_A(0, 1, 0); STAGE_B(0, 0, 0); STAGE_B(0, 1, 0);
  STAGE_B(32768, 0, 1); STAGE_B(32768, 1, 1);
  VMC4;   // tile0's 8 loads landed; Bod(1) outstanding
  bar();

  int niter = K >> 7;  // 2 K-tiles per iteration
  for (int it = 0; it < niter; ++it) {
    int to = 2 * it + 1, t2 = 2 * it + 2, t3 = 2 * it + 3;
    bool nl = (it + 1 < niter);
    // ph1: read a0-3(E) + bLo(E) (12 reads); stage Aod h0 (tile 2it+1)
    READ_A8(aB0); READ_B4(bB0, bLo);
    STAGE_A(32768, 0, to);
    bar(); LGKM0; MFMAQ(0, 0, bLo); bar();
    // ph2: read bHi(E) (4); stage Aod h1
    READ_B4(bB0 + 2048, bHi);
    STAGE_A(32768, 1, to);
    bar(); LGKM0; MFMAQ(0, 2, bHi); bar();
    // ph3: read a4-7(E) (8); stage Bev h0 (t2)  [Bev free after ph2]
    READ_A8(aB0 + 4096);
    if (nl) STAGE_B(0, 0, t2);
    bar(); LGKM0; MFMAQ(4, 2, bHi); bar();
    // ph4: no reads; stage Bev h1 (t2); counted vmcnt -> odd tile (2it+1) landed
    if (nl) { STAGE_B(0, 1, t2); VMC4; } else { VMC0; }
    bar(); MFMAQ(4, 0, bLo); bar();
    // ph5: read a0-3(O) + bLo(O); stage Aev h0 (t2)  [Aev free after ph3]
    READ_A8(aB1); READ_B4(bB1, bLo);
    if (nl) STAGE_A(0, 0, t2);
    bar(); LGKM0; MFMAQ(0, 0, bLo); bar();
    // ph6: read bHi(O); stage Aev h1 (t2)
    READ_B4(bB1 + 2048, bHi);
    if (nl) STAGE_A(0, 1, t2);
    bar(); LGKM0; MFMAQ(0, 2, bHi); bar();
    // ph7: read a4-7(O); stage Bod h0 (t3)  [Bod free after ph6]
    READ_A8(aB1 + 4096);
    if (nl) STAGE_B(32768, 0, t3);
    bar(); LGKM0; MFMAQ(4, 2, bHi); bar();
    // ph8: stage Bod h1 (t3); counted vmcnt -> even tile (t2) landed for next ph1
    if (nl) { STAGE_B(32768, 1, t3); VMC4; }
    bar(); MFMAQ(4, 0, bLo); bar();
  }

#undef READ_A8
#undef READ_B4
#undef MFMAQ
#undef STAGE_A
#undef STAGE_B

  // ---- epilogue: C/D layout col=lane&15, row=(lane>>4)*4+reg (m89-verified)
  if (fuse) {
    // up-waves park u (bf16) in LDS even buffer [2][128][128] u16 (free after final iter)
    if (wn >= 2) {
#pragma unroll
      for (int mi = 0; mi < 4; ++mi)
#pragma unroll
        for (int ni = 0; ni < 4; ++ni)
#pragma unroll
          for (int r = 0; r < 4; ++r) {
            int rloc = mi * 16 + r4 * 4 + r;
            int floc = (wn - 2) * 64 + ni * 16 + c4;
            sm[(wm * 128 + rloc) * 128 + floc] = f2bf(acc[mi + 4 * 0][ni][r]);
          }
    }
    __syncthreads();
    if (wn < 2) {
#pragma unroll
      for (int mi = 0; mi < 4; ++mi)
#pragma unroll
        for (int r = 0; r < 4; ++r) {
          int rloc = mi * 16 + r4 * 4 + r;
          int lr = wm * 128 + rloc;
          if (mt * 256 + lr < segM) {
            long base = (long)(seg0 + mt * 256 + lr) * (N >> 1) + nt * 128 + wn * 64 + c4;
#pragma unroll
            for (int ni = 0; ni < 4; ++ni) {
              float g = acc[mi][ni][r];
              float u = bf2f(sm[(wm * 128 + rloc) * 128 + wn * 64 + ni * 16 + c4]);
              float a = g / (1.f + __expf(-g)) * u;
              C[base + ni * 16] = f2bf(a);
            }
          }
        }
    }
    // NOTE: only acc[0..3] (mi<4) used above for up-waves: up rows == gate rows, and
    // each wave's full 8-mi range covers rows 0..127; mi 4..7 handled below.
    if (wn >= 2) {
      // second half of rows (mi 4..7) must also be parked+consumed: do a second pass.
    }
    __syncthreads();
    if (wn >= 2) {
#pragma unroll
      for (int mi = 0; mi < 4; ++mi)
#pragma unroll
        for (int ni = 0; ni < 4; ++ni)
#pragma unroll
          for (int r = 0; r < 4; ++r) {
            int rloc = mi * 16 + r4 * 4 + r;
            int floc = (wn - 2) * 64 + ni * 16 + c4;
            sm[(wm * 128 + rloc) * 128 + floc] = f2bf(acc[mi + 4][ni][r]);
          }
    }
    __syncthreads();
    if (wn < 2) {
#pragma unroll
      for (int mi = 0; mi < 4; ++mi)
#pragma unroll
        for (int r = 0; r < 4; ++r) {
          int rloc = mi * 16 + r4 * 4 + r;
          int lr = wm * 128 + 64 + rloc;  // mi+4 block = rows 64..127 of the wave's 128
          if (mt * 256 + lr < segM) {
            long base = (long)(seg0 + mt * 256 + lr) * (N >> 1) + nt * 128 + wn * 64 + c4;
#pragma unroll
            for (int ni = 0; ni < 4; ++ni) {
              float g = acc[mi + 4][ni][r];
              float u = bf2f(sm[(wm * 128 + rloc) * 128 + wn * 64 + ni * 16 + c4]);
              float a = g / (1.f + __expf(-g)) * u;
              C[base + ni * 16] = f2bf(a);
            }
          }
        }
    }
  } else {
#pragma unroll
    for (int mi = 0; mi < 8; ++mi) {
#pragma unroll
      for (int r = 0; r < 4; ++r) {
        int lr = wm * 128 + mi * 16 + r4 * 4 + r;
        if (mt * 256 + lr < segM) {
          long base = (long)(seg0 + mt * 256 + lr) * N + nt * 256 + wn * 64 + c4;
#pragma unroll
          for (int ni = 0; ni < 4; ++ni) C[base + ni * 16] = f2bf(acc[mi][ni][r]);
        }
      }
    }
  }
}

extern "C" void kernel_launch(void* const* d_in, const int* in_sizes, int n_in,
                              void* d_out, int out_size, void* d_ws, size_t ws_size,
                              hipStream_t stream) {
  const float* hidden = (const float*)d_in[0];       // [4096, 2048]
  const float* gate_weight = (const float*)d_in[1];  // [16, 2048]
  const float* bias = (const float*)d_in[2];         // [16]
  const float* gate_w = (const float*)d_in[3];       // [16, 1024, 2048]
  const float* up_w = (const float*)d_in[4];         // [16, 1024, 2048]
  const float* down_w = (const float*)d_in[5];       // [16, 2048, 1024]
  const float* shg = (const float*)d_in[6];          // [2048, 2048]
  const float* shu = (const float*)d_in[7];          // [2048, 2048]
  const float* shd = (const float*)d_in[8];          // [2048, 2048]
  float* out = (float*)d_out;                        // [4096, 2048]

  char* p = (char*)d_ws;
  auto alloc = [&](size_t bytes) {
    char* q = p;
    p += (bytes + 255) & ~(size_t)255;
    return q;
  };
  u16* Xb = (u16*)alloc((size_t)NTOK * HDIM * 2);                 // 16 MB bf16 hidden
  u16* GUb = (u16*)alloc((size_t)NEXP * 2 * FMOE * HDIM * 2);     // 128 MB [e][interleaved g|u]
  u16* Db = (u16*)alloc((size_t)NEXP * HDIM * FMOE * 2);          // 64 MB
  u16* SGUb = (u16*)alloc((size_t)2 * FSH * HDIM * 2);            // 16 MB interleaved g|u
  u16* SDb = (u16*)alloc((size_t)HDIM * FSH * 2);                 // 8 MB
  u16* gu_out = (u16*)alloc((size_t)NTOK * 4 * FMOE * 2);         // 32 MB routed ACT (compact)
  int* topki = (int*)alloc((size_t)NTOK * 4 * 4);
  float* topkw = (float*)alloc((size_t)NTOK * 4 * 4);
  int* offs = (int*)alloc(128);
  int* ltok = (int*)alloc((size_t)NTOK * 4 * 4);
  int* slotmap = (int*)alloc((size_t)NTOK * 4 * 4);
  // aliases into GUb, valid AFTER the routed gate/up GEMM consumed the weights:
  u16* Y = GUb;                                                   // 64 MB routed down out
  u16* gs_out = GUb + (size_t)NTOK * 4 * HDIM;                    // 16 MB shared ACT (compact)
  u16* SY = gs_out + (size_t)NTOK * FSH;                          // 16 MB shared down out

  // fp32 -> bf16 conversions
  cvt_bf16<<<8192, 256, 0, stream>>>(hidden, Xb, (long)NTOK * HDIM / 4);
  cvt_pair<FMOE><<<dim3(2048, 1, NEXP), 256, 0, stream>>>(gate_w, up_w, GUb);
  cvt_bf16<<<32768, 256, 0, stream>>>(down_w, Db, (long)NEXP * HDIM * FMOE / 4);
  cvt_pair<FSH><<<dim3(4096, 1, 1), 256, 0, stream>>>(shg, shu, SGUb);
  cvt_bf16<<<4096, 256, 0, stream>>>(shd, SDb, (long)HDIM * FSH / 4);

  // routing + expert lists (atomic-free, LDS-free)
  routing_kernel<<<NTOK / 4, 256, 0, stream>>>(hidden, gate_weight, bias, topki, topkw);
  count_prefix<<<1, 256, 0, stream>>>(topki, offs);
  fill_lists<<<NEXP, 256, 0, stream>>>(topki, offs, ltok, slotmap);

  // routed gate+up GEMM with FUSED silu -> compact act [rows x FMOE]
  gemm256<<<dim3(2 * FMOE / 256, NTOK / 256, NEXP), 512, 0, stream>>>(
      Xb, GUb, gu_out, ltok, offs, 0, 2 * FMOE, HDIM, HDIM, (long)2 * FMOE * HDIM, 1);
  // routed down: [rows x 2048] = act @ D[e]^T
  gemm256<<<dim3(HDIM / 256, NTOK / 256, NEXP), 512, 0, stream>>>(
      gu_out, Db, Y, nullptr, offs, 0, HDIM, FMOE, FMOE, (long)HDIM * FMOE, 0);

  // shared expert: fused gate+up+silu, then down
  gemm256<<<dim3(2 * FSH / 256, NTOK / 256, 1), 512, 0, stream>>>(
      Xb, SGUb, gs_out, nullptr, nullptr, NTOK, 2 * FSH, HDIM, HDIM, 0, 1);
  gemm256<<<dim3(HDIM / 256, NTOK / 256, 1), 512, 0, stream>>>(
      gs_out, SDb, SY, nullptr, nullptr, NTOK, HDIM, FSH, FSH, 0, 0);

  // final: out[t] = SY[t] + sum_k w * Y[slot]
  reduce_out<<<8192, 256, 0, stream>>>(SY, Y, slotmap, topkw, out);
}